// Round 5
// baseline (334.672 us; speedup 1.0000x reference)
//
#include <hip/hip_runtime.h>

typedef __bf16 bf16x8 __attribute__((ext_vector_type(8)));
typedef short short8 __attribute__((ext_vector_type(8)));
typedef float f32x4 __attribute__((ext_vector_type(4)));
typedef unsigned short ushort_t;

// ---------- helpers ----------
__device__ __forceinline__ ushort_t f2bf(float f) {
  union { float f; unsigned u; } v; v.f = f;
  unsigned r = v.u + 0x7fffu + ((v.u >> 16) & 1u);   // RNE
  return (ushort_t)(r >> 16);
}

__device__ __forceinline__ void g2lds16(const void* g, void* l) {
  __builtin_amdgcn_global_load_lds(
      (const __attribute__((address_space(1))) void*)g,
      (__attribute__((address_space(3))) void*)l, 16, 0, 0);
}

__device__ __forceinline__ float rlane(float v, int l) {
  return __int_as_float(__builtin_amdgcn_readlane(__float_as_int(v), l));
}

__device__ __forceinline__ float fexp2(float x) {
#if __has_builtin(__builtin_amdgcn_exp2f)
  return __builtin_amdgcn_exp2f(x);
#else
  return exp2f(x);
#endif
}

template<int CTRL>
__device__ __forceinline__ float dpp_step(float x) {
  int t = __builtin_amdgcn_update_dpp(0, __float_as_int(x), CTRL, 0xf, 0xf, false);
  return x + __int_as_float(t);
}
// full 64-lane sum; result valid on lane 63
__device__ __forceinline__ float wave_sum64(float v) {
  v = dpp_step<0x111>(v);  // row_shr:1
  v = dpp_step<0x112>(v);  // row_shr:2
  v = dpp_step<0x114>(v);  // row_shr:4
  v = dpp_step<0x118>(v);  // row_shr:8
  v = dpp_step<0x142>(v);  // row_bcast:15
  v = dpp_step<0x143>(v);  // row_bcast:31
  return v;
}

// ---------- conversion / transpose ----------
__global__ __launch_bounds__(256) void conv_f32_bf16(const float* __restrict__ in,
                                                     ushort_t* __restrict__ outp) {
  int i = (blockIdx.x * 256 + threadIdx.x) * 4;
  float4 v = *(const float4*)(in + i);
  union { ushort_t u[4]; uint2 v2; } o;
  o.u[0] = f2bf(v.x); o.u[1] = f2bf(v.y); o.u[2] = f2bf(v.z); o.u[3] = f2bf(v.w);
  *(uint2*)(outp + i) = o.v2;
}

// W [K][N] f32 -> Wt [N][K] bf16
__global__ __launch_bounds__(256) void transpose_kernel(const float* __restrict__ W,
                                                        ushort_t* __restrict__ Wt,
                                                        int K, int N) {
  __shared__ float tile[32][33];
  const int n0 = blockIdx.x * 32, k0 = blockIdx.y * 32;
  const int tx = threadIdx.x & 31, ty = threadIdx.x >> 5;  // 32x8
#pragma unroll
  for (int r = 0; r < 32; r += 8)
    tile[ty + r][tx] = W[(size_t)(k0 + ty + r) * N + n0 + tx];
  __syncthreads();
#pragma unroll
  for (int r = 0; r < 32; r += 8)
    Wt[(size_t)(n0 + ty + r) * K + k0 + tx] = f2bf(tile[tx][ty + r]);
}

// ---------- bf16 MFMA GEMM (m97 structure: 128x128 tile, BK=32, 4 waves) ----------
// MODE 0: xs=silu / sres=silu split (out0 f32, out1 bf16, out2 f32)
// MODE 1: out0 = v (ldc 1664); cols 64..127 also -> out1 bf16 (delta_in, ld 64)
// MODE 2: out0 = v + resid[id] (ldc 768)
// MODE 3: out0 = min(softplus(v + resid[n]), 10) (ldc 1536)  [resid = b_dt]
template<int MODE>
__global__ __launch_bounds__(256)
void gemm_bf16(const ushort_t* __restrict__ A, const ushort_t* __restrict__ Bt,
               const int K, float* __restrict__ out0, ushort_t* __restrict__ out1,
               float* __restrict__ out2, const float* __restrict__ resid) {
  __shared__ __align__(16) ushort_t Asl[128 * 32];
  __shared__ __align__(16) ushort_t Bsl[128 * 32];
  const int tid = threadIdx.x;
  const int lane = tid & 63;
  const int wid = tid >> 6;
  const int wm = wid >> 1, wn = wid & 1;
  const int lr = lane & 15, lk = lane >> 4;
  const int bm = blockIdx.y, bn = blockIdx.x;
  const ushort_t* Ab = A + (size_t)bm * 128 * K;
  const ushort_t* Bb = Bt + (size_t)bn * 128 * K;

  f32x4 acc[4][4];
#pragma unroll
  for (int i = 0; i < 4; ++i)
#pragma unroll
    for (int j = 0; j < 4; ++j) acc[i][j] = (f32x4){0.f, 0.f, 0.f, 0.f};

  for (int k0 = 0; k0 < K; k0 += 32) {
#pragma unroll
    for (int it = 0; it < 2; ++it) {
      const int cb = ((it << 2) + wid) << 6;   // wave-uniform chunk base
      const int ch = cb + lane;
      const int row = ch >> 2;
      const int c8 = (ch & 3) << 3;
      g2lds16(Ab + (size_t)row * K + k0 + c8, Asl + (size_t)cb * 8);
      g2lds16(Bb + (size_t)row * K + k0 + c8, Bsl + (size_t)cb * 8);
    }
    __syncthreads();
    short8 av[4], bv[4];
#pragma unroll
    for (int i = 0; i < 4; ++i)
      av[i] = *(const short8*)(Asl + ((wm * 64 + i * 16 + lr) * 32 + lk * 8));
#pragma unroll
    for (int j = 0; j < 4; ++j)
      bv[j] = *(const short8*)(Bsl + ((wn * 64 + j * 16 + lr) * 32 + lk * 8));
#pragma unroll
    for (int i = 0; i < 4; ++i)
#pragma unroll
      for (int j = 0; j < 4; ++j)
        acc[i][j] = __builtin_amdgcn_mfma_f32_16x16x32_bf16(
            __builtin_bit_cast(bf16x8, av[i]), __builtin_bit_cast(bf16x8, bv[j]),
            acc[i][j], 0, 0, 0);
    __syncthreads();
  }

  const int mb = bm * 128 + wm * 64 + (lane >> 4) * 4;
  const int nb = bn * 128 + wn * 64 + (lane & 15);
#pragma unroll
  for (int i = 0; i < 4; ++i) {
#pragma unroll
    for (int j = 0; j < 4; ++j) {
      const int n = nb + j * 16;
#pragma unroll
      for (int r = 0; r < 4; ++r) {
        const int m = mb + i * 16 + r;
        float v = acc[i][j][r];
        if (MODE == 0) {
          float sv = v / (1.f + __expf(-v));   // silu
          if (n < 1536) {
            out0[(size_t)m * 1536 + n] = sv;
            out1[(size_t)m * 1536 + n] = f2bf(sv);
          } else {
            out2[(size_t)m * 1536 + (n - 1536)] = sv;
          }
        } else if (MODE == 1) {
          out0[(size_t)m * 1664 + n] = v;
          if (n >= 64 && n < 128) out1[(size_t)m * 64 + (n - 64)] = f2bf(v);
        } else if (MODE == 2) {
          const size_t id = (size_t)m * 768 + n;
          out0[id] = v + resid[id];
        } else {
          float a = v + resid[n];
          float sp = fmaxf(a, 0.f) + log1pf(__expf(-fabsf(a)));
          out0[(size_t)m * 1536 + n] = fminf(sp, 10.f);
        }
      }
    }
  }
}

// ---------- selective scan: wave per (b,d), lane = state s ----------
// Per 64-step chunk: B tile staged TRANSPOSED in LDS ([s][t], stride 68 ->
// 16B-aligned rows); lane=s reads its own row contiguously via ds_read_b128,
// prefetched one 8-step group ahead. Staging loads (coalesced float4) issued
// at chunk top, transposed ds_writes at chunk bottom, ONE barrier per chunk.
// Inner step is pure VALU: readlane broadcasts + exp2 + fma + DPP sum.
__global__ __launch_bounds__(256, 3)
void scan_kernel(const float* __restrict__ xdbl, const float* __restrict__ delta,
                 const float* __restrict__ xs, const float* __restrict__ sres,
                 const float* __restrict__ A_log, const float* __restrict__ Dp,
                 ushort_t* __restrict__ ybf) {
  __shared__ __align__(16) float Bl[2][64 * 68];
  const int tid = threadIdx.x;
  const int lane = tid & 63;
  const int wid = tid >> 6;
  const int bi = blockIdx.x;              // 0..767
  const int b = (bi >= 384) ? 1 : 0;
  const int d = (bi - b * 384) * 4 + wid; // 0..1535
  const float Aval2 = -__expf(A_log[d * 64 + lane]) * 1.44269504f;  // * log2(e)
  const float dp = Dp[d];
  const size_t r0 = (size_t)b * 1024;

  auto g_dt = [&](int t0) { return delta[(r0 + t0 + lane) * 1536 + d]; };
  auto g_xs = [&](int t0) { return xs   [(r0 + t0 + lane) * 1536 + d]; };
  auto g_rs = [&](int t0) { return sres [(r0 + t0 + lane) * 1536 + d]; };
  auto g_Ct = [&](int t0) { return xdbl [(r0 + t0 + lane) * 1664 + 128 + d]; };

  float4 st[4];
  // stage chunk 0: coalesced float4 row loads -> transposed LDS write
#pragma unroll
  for (int i = 0; i < 4; ++i) {
    int q = i * 256 + tid;                 // float4 index: row=q>>4, col4=q&15
    st[i] = *(const float4*)(xdbl + (r0 + (q >> 4)) * 1664 + ((q & 15) << 2));
  }
#pragma unroll
  for (int i = 0; i < 4; ++i) {
    int q = i * 256 + tid;
    int t = q >> 4, s0 = (q & 15) << 2;
    Bl[0][(s0 + 0) * 68 + t] = st[i].x;
    Bl[0][(s0 + 1) * 68 + t] = st[i].y;
    Bl[0][(s0 + 2) * 68 + t] = st[i].z;
    Bl[0][(s0 + 3) * 68 + t] = st[i].w;
  }
  float dtv = g_dt(0), xtv = g_xs(0), rtv = g_rs(0), Ctv = g_Ct(0);
  float h = 0.f;
  __syncthreads();

  for (int c = 0; c < 16; ++c) {
    const int t0c = c << 6;
    // issue next-chunk staging loads + scalar gathers (hidden under compute)
    float ndt = dtv, nxt = xtv, nrt = rtv, nCt = Ctv;
    if (c < 15) {
#pragma unroll
      for (int i = 0; i < 4; ++i) {
        int q = i * 256 + tid;
        st[i] = *(const float4*)(xdbl + (r0 + t0c + 64 + (q >> 4)) * 1664 +
                                 ((q & 15) << 2));
      }
      ndt = g_dt(t0c + 64); nxt = g_xs(t0c + 64);
      nrt = g_rs(t0c + 64); nCt = g_Ct(t0c + 64);
    }

    const float dxv = dtv * xtv;
    const float* Bs = &Bl[c & 1][lane * 68];
    float4 bq0 = *(const float4*)(Bs + 0);
    float4 bq1 = *(const float4*)(Bs + 4);
    float yacc = 0.f;
#pragma unroll
    for (int g = 0; g < 8; ++g) {
      float4 cur0 = bq0, cur1 = bq1;
      if (g < 7) {                          // prefetch next 8-step group
        bq0 = *(const float4*)(Bs + (g + 1) * 8);
        bq1 = *(const float4*)(Bs + (g + 1) * 8 + 4);
      }
      float bv[8] = {cur0.x, cur0.y, cur0.z, cur0.w,
                     cur1.x, cur1.y, cur1.z, cur1.w};
#pragma unroll
      for (int j = 0; j < 8; ++j) {
        const int tt = g * 8 + j;
        float sdt = rlane(dtv, tt);
        float sdx = rlane(dxv, tt);
        float dA = fexp2(sdt * Aval2);
        h = fmaf(dA, h, sdx * bv[j]);
        float S = wave_sum64(h);
        float Sb = rlane(S, 63);
        yacc = (lane == tt) ? Sb : yacc;
      }
    }
    // chunk epilogue: fused (y + xs*Dp) * silu(res), lane = t
    ybf[(r0 + t0c + lane) * 1536 + d] = f2bf((Ctv * yacc + xtv * dp) * rtv);

    // transposed write of next chunk's B tile into the other buffer
    if (c < 15) {
#pragma unroll
      for (int i = 0; i < 4; ++i) {
        int q = i * 256 + tid;
        int t = q >> 4, s0 = (q & 15) << 2;
        float* Bw = &Bl[(c + 1) & 1][0];
        Bw[(s0 + 0) * 68 + t] = st[i].x;
        Bw[(s0 + 1) * 68 + t] = st[i].y;
        Bw[(s0 + 2) * 68 + t] = st[i].z;
        Bw[(s0 + 3) * 68 + t] = st[i].w;
      }
    }
    dtv = ndt; xtv = nxt; rtv = nrt; Ctv = nCt;
    __syncthreads();
  }
}

// ---------- LayerNorm (row = 768) ----------
__global__ __launch_bounds__(256)
void ln_kernel(const float* __restrict__ in, const float* __restrict__ g,
               const float* __restrict__ be, float* __restrict__ outp) {
  const int row = blockIdx.x, tid = threadIdx.x;
  const float* p = in + (size_t)row * 768;
  float v0 = p[tid], v1 = p[tid + 256], v2 = p[tid + 512];
  __shared__ float sb[4];
  const int wid = tid >> 6;
  float s = wave_sum64(v0 + v1 + v2);
  if ((tid & 63) == 63) sb[wid] = s;
  __syncthreads();
  float mu = (sb[0] + sb[1] + sb[2] + sb[3]) * (1.f / 768.f);
  __syncthreads();
  float d0 = v0 - mu, d1 = v1 - mu, d2 = v2 - mu;
  float q = wave_sum64(d0 * d0 + d1 * d1 + d2 * d2);
  if ((tid & 63) == 63) sb[wid] = q;
  __syncthreads();
  float var = (sb[0] + sb[1] + sb[2] + sb[3]) * (1.f / 768.f);
  float inv = rsqrtf(var + 1e-5f);
  float* po = outp + (size_t)row * 768;
  po[tid]       = d0 * inv * g[tid]       + be[tid];
  po[tid + 256] = d1 * inv * g[tid + 256] + be[tid + 256];
  po[tid + 512] = d2 * inv * g[tid + 512] + be[tid + 512];
}

// ---------- launch ----------
extern "C" void kernel_launch(void* const* d_in, const int* in_sizes, int n_in,
                              void* d_out, int out_size, void* d_ws, size_t ws_size,
                              hipStream_t stream) {
  (void)in_sizes; (void)n_in; (void)out_size; (void)ws_size;
  const float* x     = (const float*)d_in[0];
  const float* W_in  = (const float*)d_in[1];
  const float* W_x   = (const float*)d_in[2];
  const float* W_dt  = (const float*)d_in[3];
  const float* b_dt  = (const float*)d_in[4];
  const float* A_log = (const float*)d_in[5];
  const float* Dp    = (const float*)d_in[6];
  const float* W_out = (const float*)d_in[7];
  const float* ln_g  = (const float*)d_in[8];
  const float* ln_b  = (const float*)d_in[9];
  float* out = (float*)d_out;
  char* ws = (char*)d_ws;

  ushort_t* xbf   = (ushort_t*)(ws + 0);          // 2048x768 bf16
  ushort_t* WinT  = (ushort_t*)(ws + 3145728);    // 3072x768 bf16
  ushort_t* WxT   = (ushort_t*)(ws + 7864320);    // 1664x1536 bf16
  ushort_t* WoutT = (ushort_t*)(ws + 12976128);   // 768x1536 bf16
  float*    xs_f  = (float*)   (ws + 15335424);   // 2048x1536 f32
  ushort_t* xs_bf = (ushort_t*)(ws + 27918336);   // 2048x1536 bf16
  float*    sresp = (float*)   (ws + 34209792);   // 2048x1536 f32 (silu(res))
  float*    xdbl  = (float*)   (ws + 46792704);   // 2048x1664 f32
  float*    dlt   = (float*)   (ws + 60424192);   // 2048x1536 f32
  ushort_t* ybf   = (ushort_t*)(ws + 73007104);   // 2048x1536 bf16
  float*    otmp  = (float*)   (ws + 79298560);   // 2048x768 f32
  ushort_t* dbf   = (ushort_t*)(ws + 85590016);   // 2048x64 bf16 (delta_in)
  ushort_t* WdtT  = (ushort_t*)(ws + 85852160);   // 1536x64 bf16

  conv_f32_bf16<<<1536, 256, 0, stream>>>(x, xbf);
  transpose_kernel<<<dim3(96, 24), 256, 0, stream>>>(W_in, WinT, 768, 3072);
  transpose_kernel<<<dim3(52, 48), 256, 0, stream>>>(W_x, WxT, 1536, 1664);
  transpose_kernel<<<dim3(24, 48), 256, 0, stream>>>(W_out, WoutT, 1536, 768);
  transpose_kernel<<<dim3(48, 2), 256, 0, stream>>>(W_dt, WdtT, 64, 1536);

  gemm_bf16<0><<<dim3(24, 16), 256, 0, stream>>>(xbf, WinT, 768, xs_f, xs_bf, sresp, nullptr);
  gemm_bf16<1><<<dim3(13, 16), 256, 0, stream>>>(xs_bf, WxT, 1536, xdbl, dbf, nullptr, nullptr);
  gemm_bf16<3><<<dim3(12, 16), 256, 0, stream>>>(dbf, WdtT, 64, dlt, nullptr, nullptr, b_dt);
  scan_kernel<<<768, 256, 0, stream>>>(xdbl, dlt, xs_f, sresp, A_log, Dp, ybf);
  gemm_bf16<2><<<dim3(6, 16), 256, 0, stream>>>(ybf, WoutT, 1536, otmp, nullptr, nullptr, x);
  ln_kernel<<<2048, 256, 0, stream>>>(otmp, ln_g, ln_b, out);
}

// Round 6
// 289.531 us; speedup vs baseline: 1.1559x; 1.1559x over previous
//
#include <hip/hip_runtime.h>

typedef __bf16 bf16x8 __attribute__((ext_vector_type(8)));
typedef short short8 __attribute__((ext_vector_type(8)));
typedef float f32x4 __attribute__((ext_vector_type(4)));
typedef unsigned short ushort_t;

// ---------- helpers ----------
__device__ __forceinline__ ushort_t f2bf(float f) {
  union { float f; unsigned u; } v; v.f = f;
  unsigned r = v.u + 0x7fffu + ((v.u >> 16) & 1u);   // RNE
  return (ushort_t)(r >> 16);
}

__device__ __forceinline__ void g2lds16(const void* g, void* l) {
  __builtin_amdgcn_global_load_lds(
      (const __attribute__((address_space(1))) void*)g,
      (__attribute__((address_space(3))) void*)l, 16, 0, 0);
}

__device__ __forceinline__ float rlane(float v, int l) {
  return __int_as_float(__builtin_amdgcn_readlane(__float_as_int(v), l));
}

__device__ __forceinline__ float fexp2(float x) {
#if __has_builtin(__builtin_amdgcn_exp2f)
  return __builtin_amdgcn_exp2f(x);
#else
  return exp2f(x);
#endif
}

template<int CTRL>
__device__ __forceinline__ float dpp_step(float x) {
  int t = __builtin_amdgcn_update_dpp(0, __float_as_int(x), CTRL, 0xf, 0xf, false);
  return x + __int_as_float(t);
}
// full 64-lane sum; result valid on lane 63
__device__ __forceinline__ float wave_sum64(float v) {
  v = dpp_step<0x111>(v);  // row_shr:1
  v = dpp_step<0x112>(v);  // row_shr:2
  v = dpp_step<0x114>(v);  // row_shr:4
  v = dpp_step<0x118>(v);  // row_shr:8
  v = dpp_step<0x142>(v);  // row_bcast:15
  v = dpp_step<0x143>(v);  // row_bcast:31
  return v;
}

// ---------- conversion / transpose ----------
__global__ __launch_bounds__(256) void conv_f32_bf16(const float* __restrict__ in,
                                                     ushort_t* __restrict__ outp) {
  int i = (blockIdx.x * 256 + threadIdx.x) * 4;
  float4 v = *(const float4*)(in + i);
  union { ushort_t u[4]; uint2 v2; } o;
  o.u[0] = f2bf(v.x); o.u[1] = f2bf(v.y); o.u[2] = f2bf(v.z); o.u[3] = f2bf(v.w);
  *(uint2*)(outp + i) = o.v2;
}

// W [K][N] f32 -> Wt [N][K] bf16
__global__ __launch_bounds__(256) void transpose_kernel(const float* __restrict__ W,
                                                        ushort_t* __restrict__ Wt,
                                                        int K, int N) {
  __shared__ float tile[32][33];
  const int n0 = blockIdx.x * 32, k0 = blockIdx.y * 32;
  const int tx = threadIdx.x & 31, ty = threadIdx.x >> 5;  // 32x8
#pragma unroll
  for (int r = 0; r < 32; r += 8)
    tile[ty + r][tx] = W[(size_t)(k0 + ty + r) * N + n0 + tx];
  __syncthreads();
#pragma unroll
  for (int r = 0; r < 32; r += 8)
    Wt[(size_t)(n0 + ty + r) * K + k0 + tx] = f2bf(tile[tx][ty + r]);
}

// ---------- bf16 MFMA GEMM (m97 structure: 128x128 tile, BK=32, 4 waves) ----------
// MODE 0: xs=silu / sres=silu split; MODE 1: out0=v (ldc 1664);
// MODE 2: out0 = v + resid (ldc 768)
template<int MODE>
__global__ __launch_bounds__(256)
void gemm_bf16(const ushort_t* __restrict__ A, const ushort_t* __restrict__ Bt,
               const int K, float* __restrict__ out0, ushort_t* __restrict__ out1,
               float* __restrict__ out2, const float* __restrict__ resid) {
  __shared__ __align__(16) ushort_t Asl[128 * 32];
  __shared__ __align__(16) ushort_t Bsl[128 * 32];
  const int tid = threadIdx.x;
  const int lane = tid & 63;
  const int wid = tid >> 6;
  const int wm = wid >> 1, wn = wid & 1;
  const int lr = lane & 15, lk = lane >> 4;
  const int bm = blockIdx.y, bn = blockIdx.x;
  const ushort_t* Ab = A + (size_t)bm * 128 * K;
  const ushort_t* Bb = Bt + (size_t)bn * 128 * K;

  f32x4 acc[4][4];
#pragma unroll
  for (int i = 0; i < 4; ++i)
#pragma unroll
    for (int j = 0; j < 4; ++j) acc[i][j] = (f32x4){0.f, 0.f, 0.f, 0.f};

  for (int k0 = 0; k0 < K; k0 += 32) {
#pragma unroll
    for (int it = 0; it < 2; ++it) {
      const int cb = ((it << 2) + wid) << 6;   // wave-uniform chunk base
      const int ch = cb + lane;
      const int row = ch >> 2;
      const int c8 = (ch & 3) << 3;
      g2lds16(Ab + (size_t)row * K + k0 + c8, Asl + (size_t)cb * 8);
      g2lds16(Bb + (size_t)row * K + k0 + c8, Bsl + (size_t)cb * 8);
    }
    __syncthreads();
    short8 av[4], bv[4];
#pragma unroll
    for (int i = 0; i < 4; ++i)
      av[i] = *(const short8*)(Asl + ((wm * 64 + i * 16 + lr) * 32 + lk * 8));
#pragma unroll
    for (int j = 0; j < 4; ++j)
      bv[j] = *(const short8*)(Bsl + ((wn * 64 + j * 16 + lr) * 32 + lk * 8));
#pragma unroll
    for (int i = 0; i < 4; ++i)
#pragma unroll
      for (int j = 0; j < 4; ++j)
        acc[i][j] = __builtin_amdgcn_mfma_f32_16x16x32_bf16(
            __builtin_bit_cast(bf16x8, av[i]), __builtin_bit_cast(bf16x8, bv[j]),
            acc[i][j], 0, 0, 0);
    __syncthreads();
  }

  const int mb = bm * 128 + wm * 64 + (lane >> 4) * 4;
  const int nb = bn * 128 + wn * 64 + (lane & 15);
#pragma unroll
  for (int i = 0; i < 4; ++i) {
#pragma unroll
    for (int j = 0; j < 4; ++j) {
      const int n = nb + j * 16;
#pragma unroll
      for (int r = 0; r < 4; ++r) {
        const int m = mb + i * 16 + r;
        float v = acc[i][j][r];
        if (MODE == 0) {
          float sv = v / (1.f + __expf(-v));   // silu
          if (n < 1536) {
            out0[(size_t)m * 1536 + n] = sv;
            out1[(size_t)m * 1536 + n] = f2bf(sv);
          } else {
            out2[(size_t)m * 1536 + (n - 1536)] = sv;
          }
        } else if (MODE == 1) {
          out0[(size_t)m * 1664 + n] = v;
        } else {
          const size_t id = (size_t)m * 768 + n;
          out0[id] = v + resid[id];
        }
      }
    }
  }
}

// ---------- delta GEMM (K=64) + softplus + clamp ----------
__global__ __launch_bounds__(256)
void dt_gemm(const float* __restrict__ xdbl, const float* __restrict__ Wdt,
             const float* __restrict__ bdt, float* __restrict__ delta) {
  __shared__ float Wl[64][256];
  __shared__ float Xl[32][64];
  const int tid = threadIdx.x;
  const int n0 = blockIdx.x << 8;
  const int m0 = blockIdx.y << 5;
  for (int i = tid; i < 64 * 256; i += 256) {
    int k = i >> 8, nn = i & 255;
    Wl[k][nn] = Wdt[(size_t)k * 1536 + n0 + nn];
  }
  for (int i = tid; i < 32 * 64; i += 256) {
    int mm = i >> 6, k = i & 63;
    Xl[mm][k] = xdbl[(size_t)(m0 + mm) * 1664 + 64 + k];   // delta_in cols 64..127
  }
  __syncthreads();
  float bv = bdt[n0 + tid];
  for (int mm = 0; mm < 32; ++mm) {
    float acc = bv;
#pragma unroll
    for (int k = 0; k < 64; ++k) acc = fmaf(Xl[mm][k], Wl[k][tid], acc);
    float sp = fmaxf(acc, 0.f) + log1pf(__expf(-fabsf(acc)));  // stable softplus
    delta[(size_t)(m0 + mm) * 1536 + n0 + tid] = fminf(sp, 10.f);
  }
}

// ---------- time-segmented selective scan ----------
// Segment = 64 steps; 16 segments. Wave = (b, d, seg); block = 4 d-channels
// sharing one B tile ([t][s] LDS layout, uniform-row b32 read = conflict-free).
//
// pass1: run segment from h=0 -> Q (end state, per s) and Dsum = sum(delta).
// combine: per (b,d): h_in_{j+1} = exp2(Aval2*Dsum_j)*h_in_j + Q_j, overwriting
//          Q_j with h_in_j in place.
// pass2: rerun segment from h_in with y output + fused elementwise tail.

__global__ __launch_bounds__(256, 8)
void scan_pass1(const float* __restrict__ xdbl, const float* __restrict__ delta,
                const float* __restrict__ xs, const float* __restrict__ A_log,
                float* __restrict__ Qb, float* __restrict__ Dsum) {
  __shared__ float Bt[64 * 64];
  const int tid = threadIdx.x;
  const int lane = tid & 63;
  const int wid = tid >> 6;
  const int seg = blockIdx.x;             // 0..15
  const int d = blockIdx.y * 4 + wid;     // 0..1535
  const int b = blockIdx.z;
  const int t0 = seg << 6;
  const size_t r0 = (size_t)b * 1024;
  const float Aval2 = -__expf(A_log[d * 64 + lane]) * 1.44269504f;

#pragma unroll
  for (int i = 0; i < 4; ++i) {
    int q = i * 256 + tid;                // row=q>>4, col4=(q&15)*4
    *(float4*)&Bt[(q >> 4) * 64 + ((q & 15) << 2)] =
        *(const float4*)(xdbl + (r0 + t0 + (q >> 4)) * 1664 + ((q & 15) << 2));
  }
  float dtv = delta[(r0 + t0 + lane) * 1536 + d];
  float xtv = xs[(r0 + t0 + lane) * 1536 + d];
  float dxv = dtv * xtv;
  __syncthreads();

  float h = 0.f;
#pragma unroll
  for (int tt = 0; tt < 64; ++tt) {
    float sdt = rlane(dtv, tt);
    float sdx = rlane(dxv, tt);
    float dA = fexp2(sdt * Aval2);
    h = fmaf(dA, h, sdx * Bt[tt * 64 + lane]);
  }
  const size_t sb = ((size_t)(b * 16 + seg) * 1536 + d);
  Qb[sb * 64 + lane] = h;
  float Ds = rlane(wave_sum64(dtv), 63);
  if (lane == 0) Dsum[sb] = Ds;
}

__global__ __launch_bounds__(256, 8)
void scan_combine(float* __restrict__ Qb, const float* __restrict__ Dsum,
                  const float* __restrict__ A_log) {
  const int tid = threadIdx.x;
  const int lane = tid & 63;
  const int wave = blockIdx.x * 4 + (tid >> 6);  // 0..3071
  const int b = wave >> 10 >> 1;                 // wave/1536 (wave<3072)
  const int bb = (wave >= 1536) ? 1 : 0;
  const int d = wave - bb * 1536;
  (void)b;
  const float Aval2 = -__expf(A_log[d * 64 + lane]) * 1.44269504f;
  float h = 0.f;
#pragma unroll
  for (int j = 0; j < 16; ++j) {
    const size_t sb = ((size_t)(bb * 16 + j) * 1536 + d);
    float q = Qb[sb * 64 + lane];
    float P = fexp2(Aval2 * Dsum[sb]);
    Qb[sb * 64 + lane] = h;               // h_in for segment j
    h = fmaf(P, h, q);
  }
}

__global__ __launch_bounds__(256, 8)
void scan_pass2(const float* __restrict__ xdbl, const float* __restrict__ delta,
                const float* __restrict__ xs, const float* __restrict__ sres,
                const float* __restrict__ A_log, const float* __restrict__ Dp,
                const float* __restrict__ Qb, ushort_t* __restrict__ ybf) {
  __shared__ float Bt[64 * 64];
  const int tid = threadIdx.x;
  const int lane = tid & 63;
  const int wid = tid >> 6;
  const int seg = blockIdx.x;
  const int d = blockIdx.y * 4 + wid;
  const int b = blockIdx.z;
  const int t0 = seg << 6;
  const size_t r0 = (size_t)b * 1024;
  const float Aval2 = -__expf(A_log[d * 64 + lane]) * 1.44269504f;
  const float dp = Dp[d];

#pragma unroll
  for (int i = 0; i < 4; ++i) {
    int q = i * 256 + tid;
    *(float4*)&Bt[(q >> 4) * 64 + ((q & 15) << 2)] =
        *(const float4*)(xdbl + (r0 + t0 + (q >> 4)) * 1664 + ((q & 15) << 2));
  }
  const size_t gi = (r0 + t0 + lane);
  float dtv = delta[gi * 1536 + d];
  float xtv = xs[gi * 1536 + d];
  float rtv = sres[gi * 1536 + d];
  float Ctv = xdbl[gi * 1664 + 128 + d];
  float dxv = dtv * xtv;
  float h = Qb[((size_t)(b * 16 + seg) * 1536 + d) * 64 + lane];
  __syncthreads();

  float yacc = 0.f;
#pragma unroll
  for (int tt = 0; tt < 64; ++tt) {
    float sdt = rlane(dtv, tt);
    float sdx = rlane(dxv, tt);
    float dA = fexp2(sdt * Aval2);
    h = fmaf(dA, h, sdx * Bt[tt * 64 + lane]);
    float S = wave_sum64(h);
    float Sb = rlane(S, 63);
    yacc = (lane == tt) ? Sb : yacc;
  }
  ybf[gi * 1536 + d] = f2bf((Ctv * yacc + xtv * dp) * rtv);
}

// ---------- LayerNorm (row = 768) ----------
__global__ __launch_bounds__(256)
void ln_kernel(const float* __restrict__ in, const float* __restrict__ g,
               const float* __restrict__ be, float* __restrict__ outp) {
  const int row = blockIdx.x, tid = threadIdx.x;
  const float* p = in + (size_t)row * 768;
  float v0 = p[tid], v1 = p[tid + 256], v2 = p[tid + 512];
  __shared__ float sb[4];
  const int wid = tid >> 6;
  float s = wave_sum64(v0 + v1 + v2);
  if ((tid & 63) == 63) sb[wid] = s;
  __syncthreads();
  float mu = (sb[0] + sb[1] + sb[2] + sb[3]) * (1.f / 768.f);
  __syncthreads();
  float d0 = v0 - mu, d1 = v1 - mu, d2 = v2 - mu;
  float q = wave_sum64(d0 * d0 + d1 * d1 + d2 * d2);
  if ((tid & 63) == 63) sb[wid] = q;
  __syncthreads();
  float var = (sb[0] + sb[1] + sb[2] + sb[3]) * (1.f / 768.f);
  float inv = rsqrtf(var + 1e-5f);
  float* po = outp + (size_t)row * 768;
  po[tid]       = d0 * inv * g[tid]       + be[tid];
  po[tid + 256] = d1 * inv * g[tid + 256] + be[tid + 256];
  po[tid + 512] = d2 * inv * g[tid + 512] + be[tid + 512];
}

// ---------- launch ----------
extern "C" void kernel_launch(void* const* d_in, const int* in_sizes, int n_in,
                              void* d_out, int out_size, void* d_ws, size_t ws_size,
                              hipStream_t stream) {
  (void)in_sizes; (void)n_in; (void)out_size; (void)ws_size;
  const float* x     = (const float*)d_in[0];
  const float* W_in  = (const float*)d_in[1];
  const float* W_x   = (const float*)d_in[2];
  const float* W_dt  = (const float*)d_in[3];
  const float* b_dt  = (const float*)d_in[4];
  const float* A_log = (const float*)d_in[5];
  const float* Dp    = (const float*)d_in[6];
  const float* W_out = (const float*)d_in[7];
  const float* ln_g  = (const float*)d_in[8];
  const float* ln_b  = (const float*)d_in[9];
  float* out = (float*)d_out;
  char* ws = (char*)d_ws;

  ushort_t* xbf   = (ushort_t*)(ws + 0);          // 2048x768 bf16   [dead after gemm0]
  ushort_t* WinT  = (ushort_t*)(ws + 3145728);    // 3072x768 bf16   [dead after gemm0]
  ushort_t* WxT   = (ushort_t*)(ws + 7864320);    // 1664x1536 bf16  [dead after gemm1]
  ushort_t* WoutT = (ushort_t*)(ws + 12976128);   // 768x1536 bf16
  float*    xs_f  = (float*)   (ws + 15335424);   // 2048x1536 f32
  ushort_t* xs_bf = (ushort_t*)(ws + 27918336);   // 2048x1536 bf16
  float*    sresp = (float*)   (ws + 34209792);   // 2048x1536 f32 (silu(res))
  float*    xdbl  = (float*)   (ws + 46792704);   // 2048x1664 f32
  float*    dlt   = (float*)   (ws + 60424192);   // 2048x1536 f32
  ushort_t* ybf   = (ushort_t*)(ws + 73007104);   // 2048x1536 bf16
  float*    otmp  = (float*)   (ws + 79298560);   // 2048x768 f32
  // scan scratch reuses the dead [0, 12.98M) region:
  float*    Qbuf  = (float*)   (ws + 0);          // 32x1536x64 f32 = 12.58MB
  float*    Dsum  = (float*)   (ws + 12582912);   // 32x1536 f32 = 196KB (< 12976128)

  conv_f32_bf16<<<1536, 256, 0, stream>>>(x, xbf);
  transpose_kernel<<<dim3(96, 24), 256, 0, stream>>>(W_in, WinT, 768, 3072);
  transpose_kernel<<<dim3(52, 48), 256, 0, stream>>>(W_x, WxT, 1536, 1664);
  transpose_kernel<<<dim3(24, 48), 256, 0, stream>>>(W_out, WoutT, 1536, 768);

  gemm_bf16<0><<<dim3(24, 16), 256, 0, stream>>>(xbf, WinT, 768, xs_f, xs_bf, sresp, nullptr);
  gemm_bf16<1><<<dim3(13, 16), 256, 0, stream>>>(xs_bf, WxT, 1536, xdbl, nullptr, nullptr, nullptr);
  dt_gemm<<<dim3(6, 64), 256, 0, stream>>>(xdbl, W_dt, b_dt, dlt);

  scan_pass1<<<dim3(16, 384, 2), 256, 0, stream>>>(xdbl, dlt, xs_f, A_log, Qbuf, Dsum);
  scan_combine<<<768, 256, 0, stream>>>(Qbuf, Dsum, A_log);
  scan_pass2<<<dim3(16, 384, 2), 256, 0, stream>>>(xdbl, dlt, xs_f, sresp, A_log, Dp, Qbuf, ybf);

  gemm_bf16<2><<<dim3(6, 16), 256, 0, stream>>>(ybf, WoutT, 1536, otmp, nullptr, nullptr, x);
  ln_kernel<<<2048, 256, 0, stream>>>(otmp, ln_g, ln_b, out);
}

// Round 7
// 245.965 us; speedup vs baseline: 1.3606x; 1.1771x over previous
//
#include <hip/hip_runtime.h>

typedef __bf16 bf16x8 __attribute__((ext_vector_type(8)));
typedef short short8 __attribute__((ext_vector_type(8)));
typedef float f32x4 __attribute__((ext_vector_type(4)));
typedef unsigned short ushort_t;

// ---------- helpers ----------
__device__ __forceinline__ ushort_t f2bf(float f) {
  union { float f; unsigned u; } v; v.f = f;
  unsigned r = v.u + 0x7fffu + ((v.u >> 16) & 1u);   // RNE
  return (ushort_t)(r >> 16);
}

__device__ __forceinline__ void g2lds16(const void* g, void* l) {
  __builtin_amdgcn_global_load_lds(
      (const __attribute__((address_space(1))) void*)g,
      (__attribute__((address_space(3))) void*)l, 16, 0, 0);
}

__device__ __forceinline__ float rlane(float v, int l) {
  return __int_as_float(__builtin_amdgcn_readlane(__float_as_int(v), l));
}

__device__ __forceinline__ float fexp2(float x) {
#if __has_builtin(__builtin_amdgcn_exp2f)
  return __builtin_amdgcn_exp2f(x);
#else
  return exp2f(x);
#endif
}

template<int CTRL>
__device__ __forceinline__ float dpp_step(float x) {
  int t = __builtin_amdgcn_update_dpp(0, __float_as_int(x), CTRL, 0xf, 0xf, false);
  return x + __int_as_float(t);
}
// full 64-lane sum; result valid on lane 63
__device__ __forceinline__ float wave_sum64(float v) {
  v = dpp_step<0x111>(v);  // row_shr:1
  v = dpp_step<0x112>(v);  // row_shr:2
  v = dpp_step<0x114>(v);  // row_shr:4
  v = dpp_step<0x118>(v);  // row_shr:8
  v = dpp_step<0x142>(v);  // row_bcast:15
  v = dpp_step<0x143>(v);  // row_bcast:31
  return v;
}
// 16-lane row sum; result valid on lane 15 of each row16
__device__ __forceinline__ float row_sum16(float v) {
  v = dpp_step<0x111>(v);
  v = dpp_step<0x112>(v);
  v = dpp_step<0x114>(v);
  v = dpp_step<0x118>(v);
  return v;
}
// broadcast lane15 of each row16 to the whole row (BitMode: and=0x10,or=0x0F)
__device__ __forceinline__ float bcast_row15(float v) {
  return __int_as_float(__builtin_amdgcn_ds_swizzle(__float_as_int(v), 0x1F0));
}

// ---------- conversion / transpose ----------
__global__ __launch_bounds__(256) void conv_f32_bf16(const float* __restrict__ in,
                                                     ushort_t* __restrict__ outp) {
  int i = (blockIdx.x * 256 + threadIdx.x) * 4;
  float4 v = *(const float4*)(in + i);
  union { ushort_t u[4]; uint2 v2; } o;
  o.u[0] = f2bf(v.x); o.u[1] = f2bf(v.y); o.u[2] = f2bf(v.z); o.u[3] = f2bf(v.w);
  *(uint2*)(outp + i) = o.v2;
}

// W [K][N] f32 -> Wt [N][K] bf16
__global__ __launch_bounds__(256) void transpose_kernel(const float* __restrict__ W,
                                                        ushort_t* __restrict__ Wt,
                                                        int K, int N) {
  __shared__ float tile[32][33];
  const int n0 = blockIdx.x * 32, k0 = blockIdx.y * 32;
  const int tx = threadIdx.x & 31, ty = threadIdx.x >> 5;  // 32x8
#pragma unroll
  for (int r = 0; r < 32; r += 8)
    tile[ty + r][tx] = W[(size_t)(k0 + ty + r) * N + n0 + tx];
  __syncthreads();
#pragma unroll
  for (int r = 0; r < 32; r += 8)
    Wt[(size_t)(n0 + ty + r) * K + k0 + tx] = f2bf(tile[tx][ty + r]);
}

// ---------- bf16 MFMA GEMM (m97 structure: 128x128 tile, BK=32, 4 waves) ----------
template<int MODE>
__global__ __launch_bounds__(256)
void gemm_bf16(const ushort_t* __restrict__ A, const ushort_t* __restrict__ Bt,
               const int K, float* __restrict__ out0, ushort_t* __restrict__ out1,
               float* __restrict__ out2, const float* __restrict__ resid) {
  __shared__ __align__(16) ushort_t Asl[128 * 32];
  __shared__ __align__(16) ushort_t Bsl[128 * 32];
  const int tid = threadIdx.x;
  const int lane = tid & 63;
  const int wid = tid >> 6;
  const int wm = wid >> 1, wn = wid & 1;
  const int lr = lane & 15, lk = lane >> 4;
  const int bm = blockIdx.y, bn = blockIdx.x;
  const ushort_t* Ab = A + (size_t)bm * 128 * K;
  const ushort_t* Bb = Bt + (size_t)bn * 128 * K;

  f32x4 acc[4][4];
#pragma unroll
  for (int i = 0; i < 4; ++i)
#pragma unroll
    for (int j = 0; j < 4; ++j) acc[i][j] = (f32x4){0.f, 0.f, 0.f, 0.f};

  for (int k0 = 0; k0 < K; k0 += 32) {
#pragma unroll
    for (int it = 0; it < 2; ++it) {
      const int cb = ((it << 2) + wid) << 6;   // wave-uniform chunk base
      const int ch = cb + lane;
      const int row = ch >> 2;
      const int c8 = (ch & 3) << 3;
      g2lds16(Ab + (size_t)row * K + k0 + c8, Asl + (size_t)cb * 8);
      g2lds16(Bb + (size_t)row * K + k0 + c8, Bsl + (size_t)cb * 8);
    }
    __syncthreads();
    short8 av[4], bv[4];
#pragma unroll
    for (int i = 0; i < 4; ++i)
      av[i] = *(const short8*)(Asl + ((wm * 64 + i * 16 + lr) * 32 + lk * 8));
#pragma unroll
    for (int j = 0; j < 4; ++j)
      bv[j] = *(const short8*)(Bsl + ((wn * 64 + j * 16 + lr) * 32 + lk * 8));
#pragma unroll
    for (int i = 0; i < 4; ++i)
#pragma unroll
      for (int j = 0; j < 4; ++j)
        acc[i][j] = __builtin_amdgcn_mfma_f32_16x16x32_bf16(
            __builtin_bit_cast(bf16x8, av[i]), __builtin_bit_cast(bf16x8, bv[j]),
            acc[i][j], 0, 0, 0);
    __syncthreads();
  }

  const int mb = bm * 128 + wm * 64 + (lane >> 4) * 4;
  const int nb = bn * 128 + wn * 64 + (lane & 15);
#pragma unroll
  for (int i = 0; i < 4; ++i) {
#pragma unroll
    for (int j = 0; j < 4; ++j) {
      const int n = nb + j * 16;
#pragma unroll
      for (int r = 0; r < 4; ++r) {
        const int m = mb + i * 16 + r;
        float v = acc[i][j][r];
        if (MODE == 0) {
          float sv = v / (1.f + __expf(-v));   // silu
          if (n < 1536) {
            out0[(size_t)m * 1536 + n] = sv;
            out1[(size_t)m * 1536 + n] = f2bf(sv);
          } else {
            out2[(size_t)m * 1536 + (n - 1536)] = sv;
          }
        } else if (MODE == 1) {
          out0[(size_t)m * 1664 + n] = v;
        } else {
          const size_t id = (size_t)m * 768 + n;
          out0[id] = v + resid[id];
        }
      }
    }
  }
}

// ---------- delta GEMM (K=64) + softplus + clamp ----------
__global__ __launch_bounds__(256)
void dt_gemm(const float* __restrict__ xdbl, const float* __restrict__ Wdt,
             const float* __restrict__ bdt, float* __restrict__ delta) {
  __shared__ float Wl[64][256];
  __shared__ float Xl[32][64];
  const int tid = threadIdx.x;
  const int n0 = blockIdx.x << 8;
  const int m0 = blockIdx.y << 5;
  for (int i = tid; i < 64 * 256; i += 256) {
    int k = i >> 8, nn = i & 255;
    Wl[k][nn] = Wdt[(size_t)k * 1536 + n0 + nn];
  }
  for (int i = tid; i < 32 * 64; i += 256) {
    int mm = i >> 6, k = i & 63;
    Xl[mm][k] = xdbl[(size_t)(m0 + mm) * 1664 + 64 + k];   // delta_in cols 64..127
  }
  __syncthreads();
  float bv = bdt[n0 + tid];
  for (int mm = 0; mm < 32; ++mm) {
    float acc = bv;
#pragma unroll
    for (int k = 0; k < 64; ++k) acc = fmaf(Xl[mm][k], Wl[k][tid], acc);
    float sp = fmaxf(acc, 0.f) + log1pf(__expf(-fabsf(acc)));  // stable softplus
    delta[(size_t)(m0 + mm) * 1536 + n0 + tid] = fminf(sp, 10.f);
  }
}

// ---------- time-segmented selective scan, 4 channels per wave ----------
// Segment = 64 steps. Block = 4 waves = 16 channels. Per wave: lane ->
// (channel = lane>>4, states s = 4*(lane&15)..+3 in regs h0..h3).
// Per step: ds_read_b64 {dt,dx} (broadcast per 16-lane group) + ds_read_b128
// B (4 states) + 4x(mul,exp2,mul,fma) + 3 adds + 4-DPP row16 tree +
// ds_swizzle bcast + cndmask collect.

__global__ __launch_bounds__(256, 6)
void scan_pass1(const float* __restrict__ xdbl, const float* __restrict__ delta,
                const float* __restrict__ xs, const float* __restrict__ A_log,
                float* __restrict__ Qb, float* __restrict__ Dsum) {
  __shared__ __align__(16) float Bt[64 * 64];
  __shared__ __align__(16) float dtdx[16][130];   // [ch][t*2] = {dt, dt*xs}
  const int tid = threadIdx.x;
  const int lane = tid & 63;
  const int wid = tid >> 6;
  const int i16 = lane & 15;
  const int ch = wid * 4 + (lane >> 4);
  const int seg = blockIdx.x, b = blockIdx.z;
  const int d0 = blockIdx.y * 16;
  const int d = d0 + ch;
  const int t0 = seg << 6;
  const size_t r0 = (size_t)b * 1024;

  // B stage (shared by all 4 waves)
#pragma unroll
  for (int i = 0; i < 4; ++i) {
    int q = i * 256 + tid;
    *(float4*)&Bt[(q >> 4) * 64 + ((q & 15) << 2)] =
        *(const float4*)(xdbl + (r0 + t0 + (q >> 4)) * 1664 + ((q & 15) << 2));
  }
  // per-wave: gather dt/xs for this wave's 4 channels (lane = t)
  float dtg[4], dxg[4];
#pragma unroll
  for (int c = 0; c < 4; ++c) {
    int dc = d0 + wid * 4 + c;
    dtg[c] = delta[(r0 + t0 + lane) * 1536 + dc];
    dxg[c] = dtg[c] * xs[(r0 + t0 + lane) * 1536 + dc];
  }
#pragma unroll
  for (int c = 0; c < 4; ++c)
    *(float2*)&dtdx[wid * 4 + c][lane * 2] = make_float2(dtg[c], dxg[c]);

  // Dsum per channel (wave reduce of dtg)
  float ds0 = rlane(wave_sum64(dtg[0]), 63);
  float ds1 = rlane(wave_sum64(dtg[1]), 63);
  float ds2 = rlane(wave_sum64(dtg[2]), 63);
  float ds3 = rlane(wave_sum64(dtg[3]), 63);
  if (lane == 0) {
    const size_t sb0 = (size_t)(b * 16 + seg) * 1536 + d0 + wid * 4;
    *(float4*)(Dsum + sb0) = make_float4(ds0, ds1, ds2, ds3);
  }

  // A values for this lane's 4 states
  float4 Av = *(const float4*)(A_log + (size_t)d * 64 + i16 * 4);
  const float A0 = -__expf(Av.x) * 1.44269504f;
  const float A1 = -__expf(Av.y) * 1.44269504f;
  const float A2 = -__expf(Av.z) * 1.44269504f;
  const float A3 = -__expf(Av.w) * 1.44269504f;

  __syncthreads();

  const float2* dpair = (const float2*)&dtdx[ch][0];
  const float* Brow = Bt + (i16 << 2);
  float h0 = 0.f, h1 = 0.f, h2 = 0.f, h3 = 0.f;
#pragma unroll
  for (int tt = 0; tt < 64; ++tt) {
    float2 dd = dpair[tt];
    float4 bb = *(const float4*)(Brow + tt * 64);
    h0 = fmaf(fexp2(dd.x * A0), h0, dd.y * bb.x);
    h1 = fmaf(fexp2(dd.x * A1), h1, dd.y * bb.y);
    h2 = fmaf(fexp2(dd.x * A2), h2, dd.y * bb.z);
    h3 = fmaf(fexp2(dd.x * A3), h3, dd.y * bb.w);
  }
  const size_t sb = (size_t)(b * 16 + seg) * 1536 + d;
  *(float4*)(Qb + sb * 64 + i16 * 4) = make_float4(h0, h1, h2, h3);
}

__global__ __launch_bounds__(256, 8)
void scan_combine(float* __restrict__ Qb, const float* __restrict__ Dsum,
                  const float* __restrict__ A_log) {
  const int tid = threadIdx.x;
  const int lane = tid & 63;
  const int wave = blockIdx.x * 4 + (tid >> 6);  // 0..3071
  const int bb = (wave >= 1536) ? 1 : 0;
  const int d = wave - bb * 1536;
  const float Aval2 = -__expf(A_log[(size_t)d * 64 + lane]) * 1.44269504f;
  float h = 0.f;
#pragma unroll
  for (int j = 0; j < 16; ++j) {
    const size_t sb = ((size_t)(bb * 16 + j) * 1536 + d);
    float q = Qb[sb * 64 + lane];
    float P = fexp2(Aval2 * Dsum[sb]);
    Qb[sb * 64 + lane] = h;               // h_in for segment j
    h = fmaf(P, h, q);
  }
}

__global__ __launch_bounds__(256, 6)
void scan_pass2(const float* __restrict__ xdbl, const float* __restrict__ delta,
                const float* __restrict__ xs, const float* __restrict__ sres,
                const float* __restrict__ A_log, const float* __restrict__ Dp,
                const float* __restrict__ Qb, ushort_t* __restrict__ ybf) {
  __shared__ __align__(16) float Bt[64 * 64];
  __shared__ __align__(16) float dtdx[16][130];
  const int tid = threadIdx.x;
  const int lane = tid & 63;
  const int wid = tid >> 6;
  const int i16 = lane & 15;
  const int ch = wid * 4 + (lane >> 4);
  const int seg = blockIdx.x, b = blockIdx.z;
  const int d0 = blockIdx.y * 16;
  const int d = d0 + ch;
  const int t0 = seg << 6;
  const size_t r0 = (size_t)b * 1024;

#pragma unroll
  for (int i = 0; i < 4; ++i) {
    int q = i * 256 + tid;
    *(float4*)&Bt[(q >> 4) * 64 + ((q & 15) << 2)] =
        *(const float4*)(xdbl + (r0 + t0 + (q >> 4)) * 1664 + ((q & 15) << 2));
  }
  float dtg[4];
#pragma unroll
  for (int c = 0; c < 4; ++c) {
    int dc = d0 + wid * 4 + c;
    dtg[c] = delta[(r0 + t0 + lane) * 1536 + dc];
    float dxg = dtg[c] * xs[(r0 + t0 + lane) * 1536 + dc];
    *(float2*)&dtdx[wid * 4 + c][lane * 2] = make_float2(dtg[c], dxg);
  }

  float4 Av = *(const float4*)(A_log + (size_t)d * 64 + i16 * 4);
  const float A0 = -__expf(Av.x) * 1.44269504f;
  const float A1 = -__expf(Av.y) * 1.44269504f;
  const float A2 = -__expf(Av.z) * 1.44269504f;
  const float A3 = -__expf(Av.w) * 1.44269504f;
  const float dp = Dp[d];
  const size_t sb = (size_t)(b * 16 + seg) * 1536 + d;
  float4 hq = *(const float4*)(Qb + sb * 64 + i16 * 4);
  float h0 = hq.x, h1 = hq.y, h2 = hq.z, h3 = hq.w;

  __syncthreads();

  const float2* dpair = (const float2*)&dtdx[ch][0];
  const float* Brow = Bt + (i16 << 2);
  float acc0 = 0.f, acc1 = 0.f, acc2 = 0.f, acc3 = 0.f;
#pragma unroll
  for (int tt = 0; tt < 64; ++tt) {
    float2 dd = dpair[tt];
    float4 bb = *(const float4*)(Brow + tt * 64);
    h0 = fmaf(fexp2(dd.x * A0), h0, dd.y * bb.x);
    h1 = fmaf(fexp2(dd.x * A1), h1, dd.y * bb.y);
    h2 = fmaf(fexp2(dd.x * A2), h2, dd.y * bb.z);
    h3 = fmaf(fexp2(dd.x * A3), h3, dd.y * bb.w);
    float s4 = (h0 + h1) + (h2 + h3);
    float Sv = bcast_row15(row_sum16(s4));   // channel sum in all 16 lanes
    bool m = (i16 == (tt & 15));
    if ((tt >> 4) == 0) acc0 = m ? Sv : acc0;
    else if ((tt >> 4) == 1) acc1 = m ? Sv : acc1;
    else if ((tt >> 4) == 2) acc2 = m ? Sv : acc2;
    else acc3 = m ? Sv : acc3;
  }

  // epilogue: lane's acc[r] = y[ch][r*16 + i16]
  float accs[4] = {acc0, acc1, acc2, acc3};
#pragma unroll
  for (int r = 0; r < 4; ++r) {
    const size_t gi = r0 + t0 + r * 16 + i16;
    float Ct = xdbl[gi * 1664 + 128 + d];
    float xt = xs[gi * 1536 + d];
    float rt = sres[gi * 1536 + d];
    ybf[gi * 1536 + d] = f2bf((Ct * accs[r] + xt * dp) * rt);
  }
}

// ---------- LayerNorm (row = 768) ----------
__global__ __launch_bounds__(256)
void ln_kernel(const float* __restrict__ in, const float* __restrict__ g,
               const float* __restrict__ be, float* __restrict__ outp) {
  const int row = blockIdx.x, tid = threadIdx.x;
  const float* p = in + (size_t)row * 768;
  float v0 = p[tid], v1 = p[tid + 256], v2 = p[tid + 512];
  __shared__ float sb[4];
  const int wid = tid >> 6;
  float s = wave_sum64(v0 + v1 + v2);
  if ((tid & 63) == 63) sb[wid] = s;
  __syncthreads();
  float mu = (sb[0] + sb[1] + sb[2] + sb[3]) * (1.f / 768.f);
  __syncthreads();
  float d0 = v0 - mu, d1 = v1 - mu, d2 = v2 - mu;
  float q = wave_sum64(d0 * d0 + d1 * d1 + d2 * d2);
  if ((tid & 63) == 63) sb[wid] = q;
  __syncthreads();
  float var = (sb[0] + sb[1] + sb[2] + sb[3]) * (1.f / 768.f);
  float inv = rsqrtf(var + 1e-5f);
  float* po = outp + (size_t)row * 768;
  po[tid]       = d0 * inv * g[tid]       + be[tid];
  po[tid + 256] = d1 * inv * g[tid + 256] + be[tid + 256];
  po[tid + 512] = d2 * inv * g[tid + 512] + be[tid + 512];
}

// ---------- launch ----------
extern "C" void kernel_launch(void* const* d_in, const int* in_sizes, int n_in,
                              void* d_out, int out_size, void* d_ws, size_t ws_size,
                              hipStream_t stream) {
  (void)in_sizes; (void)n_in; (void)out_size; (void)ws_size;
  const float* x     = (const float*)d_in[0];
  const float* W_in  = (const float*)d_in[1];
  const float* W_x   = (const float*)d_in[2];
  const float* W_dt  = (const float*)d_in[3];
  const float* b_dt  = (const float*)d_in[4];
  const float* A_log = (const float*)d_in[5];
  const float* Dp    = (const float*)d_in[6];
  const float* W_out = (const float*)d_in[7];
  const float* ln_g  = (const float*)d_in[8];
  const float* ln_b  = (const float*)d_in[9];
  float* out = (float*)d_out;
  char* ws = (char*)d_ws;

  ushort_t* xbf   = (ushort_t*)(ws + 0);          // 2048x768 bf16   [dead after gemm0]
  ushort_t* WinT  = (ushort_t*)(ws + 3145728);    // 3072x768 bf16   [dead after gemm0]
  ushort_t* WxT   = (ushort_t*)(ws + 7864320);    // 1664x1536 bf16  [dead after gemm1]
  ushort_t* WoutT = (ushort_t*)(ws + 12976128);   // 768x1536 bf16
  float*    xs_f  = (float*)   (ws + 15335424);   // 2048x1536 f32
  ushort_t* xs_bf = (ushort_t*)(ws + 27918336);   // 2048x1536 bf16
  float*    sresp = (float*)   (ws + 34209792);   // 2048x1536 f32 (silu(res))
  float*    xdbl  = (float*)   (ws + 46792704);   // 2048x1664 f32
  float*    dlt   = (float*)   (ws + 60424192);   // 2048x1536 f32
  ushort_t* ybf   = (ushort_t*)(ws + 73007104);   // 2048x1536 bf16
  float*    otmp  = (float*)   (ws + 79298560);   // 2048x768 f32
  // scan scratch reuses the dead [0, 12.98M) region:
  float*    Qbuf  = (float*)   (ws + 0);          // 32x1536x64 f32 = 12.58MB
  float*    Dsum  = (float*)   (ws + 12582912);   // 32x1536 f32 = 196KB

  conv_f32_bf16<<<1536, 256, 0, stream>>>(x, xbf);
  transpose_kernel<<<dim3(96, 24), 256, 0, stream>>>(W_in, WinT, 768, 3072);
  transpose_kernel<<<dim3(52, 48), 256, 0, stream>>>(W_x, WxT, 1536, 1664);
  transpose_kernel<<<dim3(24, 48), 256, 0, stream>>>(W_out, WoutT, 1536, 768);

  gemm_bf16<0><<<dim3(24, 16), 256, 0, stream>>>(xbf, WinT, 768, xs_f, xs_bf, sresp, nullptr);
  gemm_bf16<1><<<dim3(13, 16), 256, 0, stream>>>(xs_bf, WxT, 1536, xdbl, nullptr, nullptr, nullptr);
  dt_gemm<<<dim3(6, 64), 256, 0, stream>>>(xdbl, W_dt, b_dt, dlt);

  scan_pass1<<<dim3(16, 96, 2), 256, 0, stream>>>(xdbl, dlt, xs_f, A_log, Qbuf, Dsum);
  scan_combine<<<768, 256, 0, stream>>>(Qbuf, Dsum, A_log);
  scan_pass2<<<dim3(16, 96, 2), 256, 0, stream>>>(xdbl, dlt, xs_f, sresp, A_log, Dp, Qbuf, ybf);

  gemm_bf16<2><<<dim3(6, 16), 256, 0, stream>>>(ybf, WoutT, 1536, otmp, nullptr, nullptr, x);
  ln_kernel<<<2048, 256, 0, stream>>>(otmp, ln_g, ln_b, out);
}